// Round 5
// baseline (185.716 us; speedup 1.0000x reference)
//
#include <hip/hip_runtime.h>
#include <math.h>

// Problem constants (B=8, S=512, T=4, D=128)
constexpr int Bdim = 8, Sdim = 512, Tdim = 4, Ddim = 128;
constexpr int M     = Bdim * Sdim * Tdim;          // 16384 keys
constexpr int NANCH = Bdim * Sdim * (Tdim - 1);    // 12288 anchors
constexpr int ELEM  = Bdim * Sdim * Tdim * Ddim;   // 2097152

typedef __bf16 bf16x8 __attribute__((ext_vector_type(8)));
typedef float f32x4 __attribute__((ext_vector_type(4)));
typedef unsigned int uint;

// Global bf16 layout in 16B slots: slot(row r, chunk c) = (r>>4)*256 + c*16 + (r&15)
// => an MFMA fragment read (fixed row-group, fixed chunk-group) is base + lane*16:
//    perfectly linear LDS access, and staging via global_load_lds is identity.

__device__ inline float waveRedSum(float v) {
#pragma unroll
  for (int off = 32; off > 0; off >>= 1) v += __shfl_down(v, off, 64);
  return v;
}

__device__ inline unsigned short f2bf(float x) {  // RNE
  unsigned int u = __float_as_uint(x);
  u += 0x7FFF + ((u >> 16) & 1);
  return (unsigned short)(u >> 16);
}

__device__ inline float fast_exp2(float x) {  // v_exp_f32: 2^x
  float r;
  asm("v_exp_f32 %0, %1" : "=v"(r) : "v"(x));
  return r;
}

__device__ inline void load_lds16(uint4* lds, const uint4* g) {
  __builtin_amdgcn_global_load_lds(
      (const __attribute__((address_space(1))) unsigned int*)g,
      (__attribute__((address_space(3))) unsigned int*)lds, 16, 0, 0);
}

// ---------------- K1: fused prep ----------------
// 256 blocks x 64 rows. Per row: sumsq via 4-thread LDS partials (no shfl),
// bf16 convert from registers, LDS-transpose -> fully coalesced uint4 stores
// in the slot layout. Plus spike/mem^2 partials.
__global__ __launch_bounds__(256) void k_prep(
    const float* __restrict__ H, const float* __restrict__ spikes,
    const float* __restrict__ mem, uint* __restrict__ Ksw, uint* __restrict__ Asw,
    float* __restrict__ scale, float* __restrict__ MiL,
    float* __restrict__ Pspike, float* __restrict__ Pmem) {
  __shared__ float ps[256];
  __shared__ uint tbuf[4096];   // 64 rows x 64 uints, slot order
  __shared__ uint abuf[3072];   // 48 anchors x 64 uints, slot order
  __shared__ float buf2[2][4];
  const int b = blockIdx.x, t = threadIdx.x;
  const int rl = t >> 2, q = t & 3;          // local row, row-quarter
  const int r = b * 64 + rl;

  float4 hv[8];
  const float4* Hrow = (const float4*)(H + (size_t)r * 128 + q * 32);
#pragma unroll
  for (int n = 0; n < 8; ++n) hv[n] = Hrow[n];
  float pss = 0.f;
#pragma unroll
  for (int n = 0; n < 8; ++n)
    pss += hv[n].x * hv[n].x + hv[n].y * hv[n].y + hv[n].z * hv[n].z + hv[n].w * hv[n].w;
  ps[t] = pss;
  __syncthreads();
  float ss = ps[rl * 4] + ps[rl * 4 + 1] + ps[rl * 4 + 2] + ps[rl * 4 + 3];
  float sc = 10.0f / fmaxf(sqrtf(ss), 1e-12f);
  const bool isA = (rl & 3) != 3;
  const int il = (rl >> 2) * 3 + (rl & 3);   // local anchor idx [0,48)
  if (q == 0) {
    scale[r] = sc;
    if (isA) MiL[b * 48 + il] = 144.269504088896f / sc;  // (100/sc)*log2e
  }
  const int gK = rl >> 4, rLow = rl & 15;
  const int gA = il >> 4, aLow = il & 15;
#pragma unroll
  for (int u = 0; u < 16; ++u) {
    int ue = u ^ q;                 // rotate to spread LDS banks across q
    int j = q * 16 + ue;            // uint index within row [0,64)
    float x = ((const float*)hv)[2 * ue];
    float y = ((const float*)hv)[2 * ue + 1];
    uint kw = ((uint)f2bf(y * sc) << 16) | (uint)f2bf(x * sc);
    tbuf[gK * 1024 + ((j >> 2) * 16 + rLow) * 4 + (j & 3)] = kw;
    if (isA) {
      uint aw = ((uint)f2bf(y) << 16) | (uint)f2bf(x);
      abuf[gA * 1024 + ((j >> 2) * 16 + aLow) * 4 + (j & 3)] = aw;
    }
  }
  __syncthreads();
  uint4* Kdst = (uint4*)(Ksw + (size_t)b * 4096);
  const uint4* tsrc = (const uint4*)tbuf;
#pragma unroll
  for (int n = 0; n < 4; ++n) Kdst[n * 256 + t] = tsrc[n * 256 + t];
  uint4* Adst = (uint4*)(Asw + (size_t)b * 3072);
  const uint4* asrc = (const uint4*)abuf;
#pragma unroll
  for (int n = 0; n < 3; ++n) Adst[n * 256 + t] = asrc[n * 256 + t];

  // spikes mean + mem^2 partials (2048 float4 per array per block)
  float ssp = 0.f, smm = 0.f;
  const float4* s4 = (const float4*)spikes;
  const float4* m4 = (const float4*)mem;
#pragma unroll
  for (int k = 0; k < 8; ++k) {
    float4 a = s4[b * 2048 + k * 256 + t];
    float4 c = m4[b * 2048 + k * 256 + t];
    ssp += a.x + a.y + a.z + a.w;
    smm += c.x * c.x + c.y * c.y + c.z * c.z + c.w * c.w;
  }
  ssp = waveRedSum(ssp);
  smm = waveRedSum(smm);
  int w = t >> 6, lane = t & 63;
  if (lane == 0) { buf2[0][w] = ssp; buf2[1][w] = smm; }
  __syncthreads();
  if (t == 0) {
    Pspike[b] = buf2[0][0] + buf2[0][1] + buf2[0][2] + buf2[0][3];
    Pmem[b]   = buf2[1][0] + buf2[1][1] + buf2[1][2] + buf2[1][3];
  }
}

// ---------------- K2: MFMA sim-GEMM + fused exp + row-sum ----------------
// 128 anchors x 1024 keys per block; A-fragments in registers; 256 keys
// (64 KB, both LDS halves) staged per barrier pair -> half the barrier drains.
constexpr int KSPLIT = 16;
constexpr int KEYS_PB = M / KSPLIT;   // 1024

__global__ __launch_bounds__(256, 2) void k_sim(
    const uint4* __restrict__ Ksw, const uint4* __restrict__ Asw,
    const float* __restrict__ MiL, float* __restrict__ sumexp) {
  __shared__ uint4 Tile[4096];  // 64 KB = two 128-key tiles
  const int tid = threadIdx.x;
  const int lane = tid & 63, w = tid >> 6;
  const int wm = w & 1, wn = w >> 1;           // quadrant selectors
  const int wmo = wm * 64;
  const int a0 = blockIdx.y * 128;
  const int k0 = blockIdx.x * KEYS_PB;
  const int lcol = lane & 15, lhi = lane >> 4;

  // stage A tile (2048 slots) into Tile[0..2048)
  {
    const uint4* src = Asw + (size_t)a0 * 16;
#pragma unroll
    for (int it = 0; it < 8; ++it)
      load_lds16(Tile + it * 256 + tid, src + it * 256 + tid);
  }
  __syncthreads();
  bf16x8 af[4][4];
#pragma unroll
  for (int mi = 0; mi < 4; ++mi)
#pragma unroll
    for (int ks = 0; ks < 4; ++ks)
      af[mi][ks] = *(const bf16x8*)(Tile + (wm * 4 + mi) * 256 + ks * 64 + lane);
  float nmiL[4][4];
#pragma unroll
  for (int mi = 0; mi < 4; ++mi)
#pragma unroll
    for (int r = 0; r < 4; ++r)
      nmiL[mi][r] = -MiL[a0 + wmo + mi * 16 + lhi * 4 + r];
  __syncthreads();  // af consumed before K staging overwrites Tile

  float rs[4][4] = {};
  for (int t2 = 0; t2 < KEYS_PB / 256; ++t2) {
    const uint4* src = Ksw + ((size_t)k0 + t2 * 256) * 16;
#pragma unroll
    for (int it = 0; it < 16; ++it)
      load_lds16(Tile + it * 256 + tid, src + it * 256 + tid);
    __syncthreads();
#pragma unroll
    for (int half = 0; half < 2; ++half) {
      f32x4 acc[4][4] = {};
#pragma unroll
      for (int ks = 0; ks < 4; ++ks) {
        bf16x8 bfr[4];
#pragma unroll
        for (int nj = 0; nj < 4; ++nj)
          bfr[nj] = *(const bf16x8*)(Tile + half * 2048 + (wn * 4 + nj) * 256 + ks * 64 + lane);
#pragma unroll
        for (int mi = 0; mi < 4; ++mi)
#pragma unroll
          for (int nj = 0; nj < 4; ++nj)
            acc[mi][nj] = __builtin_amdgcn_mfma_f32_16x16x32_bf16(af[mi][ks], bfr[nj], acc[mi][nj], 0, 0, 0);
      }
#pragma unroll
      for (int mi = 0; mi < 4; ++mi)
#pragma unroll
        for (int nj = 0; nj < 4; ++nj)
#pragma unroll
          for (int r = 0; r < 4; ++r)
            rs[mi][r] += fast_exp2(fmaf(acc[mi][nj][r], 1.44269504088896f, nmiL[mi][r]));
    }
    __syncthreads();
  }

  // reduce over 16 key-columns, one atomic per anchor per wave
#pragma unroll
  for (int mi = 0; mi < 4; ++mi)
#pragma unroll
    for (int r = 0; r < 4; ++r) {
      float v = rs[mi][r];
      v += __shfl_xor(v, 1, 64);
      v += __shfl_xor(v, 2, 64);
      v += __shfl_xor(v, 4, 64);
      v += __shfl_xor(v, 8, 64);
      if (lcol == 0) atomicAdd(&sumexp[a0 + wmo + mi * 16 + lhi * 4 + r], v);
    }
}

// ---------------- K3: diagonal (fp32) + ce masked partials ----------------
__global__ __launch_bounds__(256) void k_fin(
    const float* __restrict__ H, const float* __restrict__ scale,
    const float* __restrict__ sumexp, const int* __restrict__ targets,
    float* __restrict__ Pce, float* __restrict__ Pnv) {
  int w = threadIdx.x >> 6, lane = threadIdx.x & 63;
  int abase = blockIdx.x * 16 + w * 4;
  float ce_sum = 0.f, nv = 0.f;
#pragma unroll
  for (int ii = 0; ii < 4; ++ii) {
    int i = abase + ii;
    int arow = (i / 3) * 4 + (i % 3);
    float2 a = *(const float2*)(H + (size_t)arow * 128 + lane * 2);
    float2 k = *(const float2*)(H + (size_t)i * 128 + lane * 2);
    float d = waveRedSum(a.x * k.x + a.y * k.y);
    if (lane == 0 && targets[i / 3] != 0) {
      float sim_ii = d * scale[i];
      float Mi = 100.0f / scale[arow];
      ce_sum += Mi + __logf(sumexp[i]) - sim_ii;
      nv += 1.0f;
    }
  }
  __shared__ float buf[2][4];
  if (lane == 0) { buf[0][w] = ce_sum; buf[1][w] = nv; }
  __syncthreads();
  if (threadIdx.x == 0) {
    Pce[blockIdx.x] = buf[0][0] + buf[0][1] + buf[0][2] + buf[0][3];
    Pnv[blockIdx.x] = buf[1][0] + buf[1][1] + buf[1][2] + buf[1][3];
  }
}

// ---------------- K4: reduce partials + final 5 outputs ----------------
__global__ void k_out(const float* __restrict__ Pspike, const float* __restrict__ Pmem,
                      const float* __restrict__ Pce, const float* __restrict__ Pnv,
                      float* __restrict__ out) {
  int tid = threadIdx.x, w = tid >> 6, lane = tid & 63;
  float a = Pspike[tid], b = Pmem[tid], c = 0.f, d = 0.f;
  for (int i = tid; i < 768; i += 256) { c += Pce[i]; d += Pnv[i]; }
  a = waveRedSum(a); b = waveRedSum(b); c = waveRedSum(c); d = waveRedSum(d);
  __shared__ float buf[4][4];
  if (lane == 0) { buf[0][w] = a; buf[1][w] = b; buf[2][w] = c; buf[3][w] = d; }
  __syncthreads();
  if (tid == 0) {
    float ssp = buf[0][0] + buf[0][1] + buf[0][2] + buf[0][3];
    float smm = buf[1][0] + buf[1][1] + buf[1][2] + buf[1][3];
    float ce  = buf[2][0] + buf[2][1] + buf[2][2] + buf[2][3];
    float nv  = buf[3][0] + buf[3][1] + buf[3][2] + buf[3][3];
    float spike_rate = ssp / (float)ELEM;
    float dr = spike_rate - 0.02f;
    float spike_reg = dr * dr;
    float mem_reg = smm / (float)ELEM;
    float tcl = ce / fmaxf(nv, 1.0f);
    out[0] = tcl + 0.01f * spike_reg + 0.001f * mem_reg;
    out[1] = tcl;
    out[2] = spike_reg;
    out[3] = mem_reg;
    out[4] = spike_rate;
  }
}

extern "C" void kernel_launch(void* const* d_in, const int* in_sizes, int n_in,
                              void* d_out, int out_size, void* d_ws, size_t ws_size,
                              hipStream_t stream) {
  const float* H = (const float*)d_in[0];
  const int* targets = (const int*)d_in[1];
  const float* spikes = (const float*)d_in[2];
  const float* mem = (const float*)d_in[3];
  float* out = (float*)d_out;
  float* ws = (float*)d_ws;

  float* sumexp = ws;                     // 12288
  float* scale  = ws + 12288;             // 16384
  float* MiL    = ws + 28672;             // 12288
  float* Pspike = ws + 40960;             // 256
  float* Pmem   = ws + 41216;             // 256
  float* Pce    = ws + 41472;             // 768
  float* Pnv    = ws + 42240;             // 768
  uint*  Ksw    = (uint*)(ws + 43008);    // M*64 uints, 16B-aligned
  uint*  Asw    = Ksw + (size_t)M * 64;   // NANCH*64 uints

  hipMemsetAsync(sumexp, 0, NANCH * sizeof(float), stream);
  k_prep<<<256, 256, 0, stream>>>(H, spikes, mem, Ksw, Asw, scale, MiL, Pspike, Pmem);
  dim3 g2(KSPLIT, NANCH / 128);
  k_sim<<<g2, 256, 0, stream>>>((const uint4*)Ksw, (const uint4*)Asw, MiL, sumexp);
  k_fin<<<NANCH / 16, 256, 0, stream>>>(H, scale, sumexp, targets, Pce, Pnv);
  k_out<<<1, 256, 0, stream>>>(Pspike, Pmem, Pce, Pnv, out);
}

// Round 6
// 163.057 us; speedup vs baseline: 1.1390x; 1.1390x over previous
//
#include <hip/hip_runtime.h>
#include <math.h>

// Problem constants (B=8, S=512, T=4, D=128)
constexpr int M     = 16384;     // keys = B*S*T
constexpr int NANCH = 12288;     // anchors = B*S*(T-1)
constexpr int ELEM  = 2097152;   // B*S*T*D

typedef __bf16 bf16x8 __attribute__((ext_vector_type(8)));
typedef float f32x4 __attribute__((ext_vector_type(4)));
typedef unsigned int uint;

// bf16 slot layout (16B uint4 slots): slot(row r, chunk c) = (r>>4)*256 + c*16 + (r&15)
// -> MFMA fragment read = base + lane*16B (linear, conflict-free), staging is identity.

__device__ inline float waveRedSum(float v) {
#pragma unroll
  for (int off = 32; off > 0; off >>= 1) v += __shfl_down(v, off, 64);
  return v;
}

__device__ inline unsigned short f2bf(float x) {  // RNE
  unsigned int u = __float_as_uint(x);
  u += 0x7FFF + ((u >> 16) & 1);
  return (unsigned short)(u >> 16);
}
__device__ inline uint packbf(float x, float y) {
  return ((uint)f2bf(y) << 16) | (uint)f2bf(x);
}

__device__ inline float fast_exp2(float x) {  // v_exp_f32: 2^x
  float r;
  asm("v_exp_f32 %0, %1" : "=v"(r) : "v"(x));
  return r;
}

__device__ inline void load_lds16(uint4* lds, const uint4* g) {
  __builtin_amdgcn_global_load_lds(
      (const __attribute__((address_space(1))) unsigned int*)g,
      (__attribute__((address_space(3))) unsigned int*)lds, 16, 0, 0);
}

// ---------------- K1: fused prep (1024 blocks x 16 rows) ----------------
__global__ __launch_bounds__(256) void k_prep(
    const float* __restrict__ H, const float* __restrict__ spikes,
    const float* __restrict__ mem, uint* __restrict__ Ksw, uint* __restrict__ Asw,
    float* __restrict__ scale, float* __restrict__ MiL,
    float* __restrict__ Pspike, float* __restrict__ Pmem) {
  __shared__ float ps[512];
  __shared__ float scb[16];
  __shared__ uint tb[1024];     // 16 rows x 64 uints in slot order
  __shared__ float buf2[2][4];
  const int g = blockIdx.x, t = threadIdx.x;

  // coalesced load of the block's 16 H rows (8 KB)
  const float4* H4 = (const float4*)H + (size_t)g * 512;
  float4 fa = H4[t];
  float4 fb = H4[t + 256];
  ps[t]       = fa.x * fa.x + fa.y * fa.y + fa.z * fa.z + fa.w * fa.w;
  ps[t + 256] = fb.x * fb.x + fb.y * fb.y + fb.z * fb.z + fb.w * fb.w;
  __syncthreads();
  if (t < 16) {
    float ss = 0.f;
#pragma unroll
    for (int j = 0; j < 32; ++j) ss += ps[t * 32 + ((j + t) & 31)];  // rotated: no bank conflict
    float sc = 10.0f / fmaxf(sqrtf(ss), 1e-12f);
    scb[t] = sc;
    scale[g * 16 + t] = sc;
    if ((t & 3) != 3)
      MiL[g * 12 + (t >> 2) * 3 + (t & 3)] = 144.269504088896f / sc;  // (100/sc)*log2e
  }
  __syncthreads();

  // convert: fa belongs to row rla = t>>5, f4-within-row ja = t&31; fb to row 8+(t>>5)
  const int ja = t & 31;
  const int rla = t >> 5, rlb = 8 + (t >> 5);
  {
    float sa = scb[rla];
    uint2 ka = {packbf(fa.x * sa, fa.y * sa), packbf(fa.z * sa, fa.w * sa)};
    *(uint2*)&tb[((ja >> 1) * 16 + rla) * 4 + (ja & 1) * 2] = ka;
    float sb = scb[rlb];
    uint2 kb = {packbf(fb.x * sb, fb.y * sb), packbf(fb.z * sb, fb.w * sb)};
    *(uint2*)&tb[((ja >> 1) * 16 + rlb) * 4 + (ja & 1) * 2] = kb;
    if ((rla & 3) != 3) {  // anchor row: raw bf16 scatter to Asw slot layout
      int i = g * 12 + (rla >> 2) * 3 + (rla & 3);
      uint2 aa = {packbf(fa.x, fa.y), packbf(fa.z, fa.w)};
      *(uint2*)&Asw[((size_t)(i >> 4) * 256 + (ja >> 1) * 16 + (i & 15)) * 4 + (ja & 1) * 2] = aa;
    }
    if ((rlb & 3) != 3) {
      int i = g * 12 + (rlb >> 2) * 3 + (rlb & 3);
      uint2 aa = {packbf(fb.x, fb.y), packbf(fb.z, fb.w)};
      *(uint2*)&Asw[((size_t)(i >> 4) * 256 + (ja >> 1) * 16 + (i & 15)) * 4 + (ja & 1) * 2] = aa;
    }
  }
  __syncthreads();
  ((uint4*)Ksw)[(size_t)g * 256 + t] = ((const uint4*)tb)[t];  // coalesced 4 KB

  // spikes mean + mem^2 partials (512 float4 each per block)
  const float4* s4 = (const float4*)spikes + (size_t)g * 512;
  const float4* m4 = (const float4*)mem + (size_t)g * 512;
  float4 s0 = s4[t], s1 = s4[t + 256];
  float4 m0 = m4[t], m1 = m4[t + 256];
  float ssp = s0.x + s0.y + s0.z + s0.w + s1.x + s1.y + s1.z + s1.w;
  float smm = m0.x * m0.x + m0.y * m0.y + m0.z * m0.z + m0.w * m0.w +
              m1.x * m1.x + m1.y * m1.y + m1.z * m1.z + m1.w * m1.w;
  ssp = waveRedSum(ssp);
  smm = waveRedSum(smm);
  int w = t >> 6, lane = t & 63;
  if (lane == 0) { buf2[0][w] = ssp; buf2[1][w] = smm; }
  __syncthreads();
  if (t == 0) {
    Pspike[g] = buf2[0][0] + buf2[0][1] + buf2[0][2] + buf2[0][3];
    Pmem[g]   = buf2[1][0] + buf2[1][1] + buf2[1][2] + buf2[1][3];
  }
}

// ---------------- K2: MFMA sim-GEMM + fused exp + row-sum ----------------
// 128 anchors x 1024 keys per block; af in regs; double-buffered 32 KB K tiles
// with prefetch-before-compute; ONE barrier per 128-key tile.
constexpr int KSPLIT = 16;
constexpr int KEYS_PB = M / KSPLIT;   // 1024
constexpr int NT = KEYS_PB / 128;     // 8

__global__ __launch_bounds__(256, 2) void k_sim(
    const uint4* __restrict__ Ksw, const uint4* __restrict__ Asw,
    const float* __restrict__ MiL, float* __restrict__ sumexp) {
  __shared__ uint4 Tile[4096];  // buf0 = [0,2048), buf1 = [2048,4096)
  const int tid = threadIdx.x;
  const int lane = tid & 63, w = tid >> 6;
  const int wm = w & 1, wn = w >> 1;
  const int wmo = wm * 64;
  const int a0 = blockIdx.y * 128;
  const int k0 = blockIdx.x * KEYS_PB;
  const int lcol = lane & 15, lhi = lane >> 4;

  // stage A -> buf0 and K tile 0 -> buf1 (async)
  {
    const uint4* srcA = Asw + (size_t)a0 * 16;
    const uint4* srcK = Ksw + (size_t)k0 * 16;
#pragma unroll
    for (int it = 0; it < 8; ++it) {
      load_lds16(Tile + it * 256 + tid, srcA + it * 256 + tid);
      load_lds16(Tile + 2048 + it * 256 + tid, srcK + it * 256 + tid);
    }
  }
  __syncthreads();
  bf16x8 af[4][4];
#pragma unroll
  for (int mi = 0; mi < 4; ++mi)
#pragma unroll
    for (int ks = 0; ks < 4; ++ks)
      af[mi][ks] = *(const bf16x8*)(Tile + (wm * 4 + mi) * 256 + ks * 64 + lane);
  float nmiL[4][4];
#pragma unroll
  for (int mi = 0; mi < 4; ++mi)
#pragma unroll
    for (int r = 0; r < 4; ++r)
      nmiL[mi][r] = -MiL[a0 + wmo + mi * 16 + lhi * 4 + r];
  __syncthreads();  // all af reads complete before buf0 is reused for K

  float rs[4][4] = {};
  for (int t2 = 0; t2 < NT; ++t2) {
    uint4* cur = Tile + ((t2 & 1) ? 0 : 2048);
    uint4* nxt = Tile + ((t2 & 1) ? 2048 : 0);
    if (t2 + 1 < NT) {  // prefetch next tile while computing this one
      const uint4* src = Ksw + ((size_t)k0 + (t2 + 1) * 128) * 16;
#pragma unroll
      for (int it = 0; it < 8; ++it)
        load_lds16(nxt + it * 256 + tid, src + it * 256 + tid);
    }
    f32x4 acc[4][4] = {};
#pragma unroll
    for (int ks = 0; ks < 4; ++ks) {
      bf16x8 bfr[4];
#pragma unroll
      for (int nj = 0; nj < 4; ++nj)
        bfr[nj] = *(const bf16x8*)(cur + (wn * 4 + nj) * 256 + ks * 64 + lane);
#pragma unroll
      for (int mi = 0; mi < 4; ++mi)
#pragma unroll
        for (int nj = 0; nj < 4; ++nj)
          acc[mi][nj] = __builtin_amdgcn_mfma_f32_16x16x32_bf16(af[mi][ks], bfr[nj], acc[mi][nj], 0, 0, 0);
    }
    // fused epilogue: rs += 2^(sim*log2e - Mi*log2e)
#pragma unroll
    for (int mi = 0; mi < 4; ++mi)
#pragma unroll
      for (int nj = 0; nj < 4; ++nj)
#pragma unroll
        for (int r = 0; r < 4; ++r)
          rs[mi][r] += fast_exp2(fmaf(acc[mi][nj][r], 1.44269504088896f, nmiL[mi][r]));
    __syncthreads();  // cur reads done (next iter overwrites) + nxt staged (vmcnt drain)
  }

  // reduce over 16 key-columns, one atomic per anchor per wave
#pragma unroll
  for (int mi = 0; mi < 4; ++mi)
#pragma unroll
    for (int r = 0; r < 4; ++r) {
      float v = rs[mi][r];
      v += __shfl_xor(v, 1, 64);
      v += __shfl_xor(v, 2, 64);
      v += __shfl_xor(v, 4, 64);
      v += __shfl_xor(v, 8, 64);
      if (lcol == 0) atomicAdd(&sumexp[a0 + wmo + mi * 16 + lhi * 4 + r], v);
    }
}

// ---------------- K3: diagonal + ce partials + last-block finalize ----------------
__global__ __launch_bounds__(256) void k_fin(
    const float* __restrict__ H, const float* __restrict__ scale,
    const float* __restrict__ sumexp, const int* __restrict__ targets,
    float* __restrict__ Pce, float* __restrict__ Pnv,
    const float* __restrict__ Pspike, const float* __restrict__ Pmem,
    uint* __restrict__ cnt, float* __restrict__ out) {
  int w = threadIdx.x >> 6, lane = threadIdx.x & 63;
  int abase = blockIdx.x * 16 + w * 4;
  float ce_sum = 0.f, nv = 0.f;
#pragma unroll
  for (int ii = 0; ii < 4; ++ii) {
    int i = abase + ii;
    int arow = (i / 3) * 4 + (i % 3);
    float2 a = *(const float2*)(H + (size_t)arow * 128 + lane * 2);
    float2 k = *(const float2*)(H + (size_t)i * 128 + lane * 2);
    float d = waveRedSum(a.x * k.x + a.y * k.y);
    if (lane == 0 && targets[i / 3] != 0) {
      float sim_ii = d * scale[i];
      float Mi = 100.0f / scale[arow];
      ce_sum += Mi + __logf(sumexp[i]) - sim_ii;
      nv += 1.0f;
    }
  }
  __shared__ float buf[2][4];
  __shared__ int isLast;
  if (lane == 0) { buf[0][w] = ce_sum; buf[1][w] = nv; }
  __syncthreads();
  if (threadIdx.x == 0) {
    float pce = buf[0][0] + buf[0][1] + buf[0][2] + buf[0][3];
    float pnv = buf[1][0] + buf[1][1] + buf[1][2] + buf[1][3];
    __hip_atomic_store(&Pce[blockIdx.x], pce, __ATOMIC_RELAXED, __HIP_MEMORY_SCOPE_AGENT);
    __hip_atomic_store(&Pnv[blockIdx.x], pnv, __ATOMIC_RELAXED, __HIP_MEMORY_SCOPE_AGENT);
    __threadfence();
    uint prev = __hip_atomic_fetch_add(cnt, 1u, __ATOMIC_ACQ_REL, __HIP_MEMORY_SCOPE_AGENT);
    isLast = (prev == gridDim.x - 1);
  }
  __syncthreads();
  if (!isLast) return;

  // final reduction (device-coherent loads)
  int t = threadIdx.x;
  float a = 0.f, b = 0.f, c = 0.f, d = 0.f;
#pragma unroll
  for (int j = 0; j < 4; ++j) {
    a += __hip_atomic_load(&Pspike[t + j * 256], __ATOMIC_RELAXED, __HIP_MEMORY_SCOPE_AGENT);
    b += __hip_atomic_load(&Pmem[t + j * 256], __ATOMIC_RELAXED, __HIP_MEMORY_SCOPE_AGENT);
  }
#pragma unroll
  for (int j = 0; j < 3; ++j) {
    c += __hip_atomic_load(&Pce[t + j * 256], __ATOMIC_RELAXED, __HIP_MEMORY_SCOPE_AGENT);
    d += __hip_atomic_load(&Pnv[t + j * 256], __ATOMIC_RELAXED, __HIP_MEMORY_SCOPE_AGENT);
  }
  a = waveRedSum(a); b = waveRedSum(b); c = waveRedSum(c); d = waveRedSum(d);
  __shared__ float fb2[4][4];
  if (lane == 0) { fb2[0][w] = a; fb2[1][w] = b; fb2[2][w] = c; fb2[3][w] = d; }
  __syncthreads();
  if (t == 0) {
    float ssp = fb2[0][0] + fb2[0][1] + fb2[0][2] + fb2[0][3];
    float smm = fb2[1][0] + fb2[1][1] + fb2[1][2] + fb2[1][3];
    float ce  = fb2[2][0] + fb2[2][1] + fb2[2][2] + fb2[2][3];
    float nvt = fb2[3][0] + fb2[3][1] + fb2[3][2] + fb2[3][3];
    float spike_rate = ssp / (float)ELEM;
    float dr = spike_rate - 0.02f;
    float spike_reg = dr * dr;
    float mem_reg = smm / (float)ELEM;
    float tcl = ce / fmaxf(nvt, 1.0f);
    out[0] = tcl + 0.01f * spike_reg + 0.001f * mem_reg;
    out[1] = tcl;
    out[2] = spike_reg;
    out[3] = mem_reg;
    out[4] = spike_rate;
  }
}

extern "C" void kernel_launch(void* const* d_in, const int* in_sizes, int n_in,
                              void* d_out, int out_size, void* d_ws, size_t ws_size,
                              hipStream_t stream) {
  const float* H = (const float*)d_in[0];
  const int* targets = (const int*)d_in[1];
  const float* spikes = (const float*)d_in[2];
  const float* mem = (const float*)d_in[3];
  float* out = (float*)d_out;
  float* ws = (float*)d_ws;

  float* sumexp = ws;                      // [0, 12288)
  uint*  cnt    = (uint*)(ws + 12288);     // [12288]
  float* scale  = ws + 12296;              // +16384 -> 28680
  float* MiL    = ws + 28680;              // +12288 -> 40968
  float* Pspike = ws + 40968;              // +1024  -> 41992
  float* Pmem   = ws + 41992;              // +1024  -> 43016
  float* Pce    = ws + 43016;              // +768   -> 43784
  float* Pnv    = ws + 43784;              // +768   -> 44552
  uint*  Ksw    = (uint*)(ws + 44552);     // M*64 uints (16B aligned)
  uint*  Asw    = Ksw + (size_t)M * 64;    // NANCH*64 uints

  hipMemsetAsync(ws, 0, 12292 * sizeof(float), stream);  // sumexp + cnt
  k_prep<<<1024, 256, 0, stream>>>(H, spikes, mem, Ksw, Asw, scale, MiL, Pspike, Pmem);
  dim3 g2(KSPLIT, NANCH / 128);
  k_sim<<<g2, 256, 0, stream>>>((const uint4*)Ksw, (const uint4*)Asw, MiL, sumexp);
  k_fin<<<NANCH / 16, 256, 0, stream>>>(H, scale, sumexp, targets, Pce, Pnv,
                                        Pspike, Pmem, cnt, out);
}